// Round 4
// baseline (50.320 us; speedup 1.0000x reference)
//
#include <hip/hip_runtime.h>
#include <cstddef>

// Problem constants
#define NB 4
#define LQ 512
#define LK 512
#define QF 256
#define NH 128
#define VD 256

__device__ __forceinline__ float fexp2(float x) {
    float r; asm("v_exp_f32 %0, %1" : "=v"(r) : "v"(x)); return r;
}
__device__ __forceinline__ float frcp(float x) {
    float r; asm("v_rcp_f32 %0, %1" : "=v"(r) : "v"(x)); return r;
}
__device__ __forceinline__ void fma4(float4& acc, float s, const float4 v) {
    acc.x = __builtin_fmaf(s, v.x, acc.x);
    acc.y = __builtin_fmaf(s, v.y, acc.y);
    acc.z = __builtin_fmaf(s, v.z, acc.z);
    acc.w = __builtin_fmaf(s, v.w, acc.w);
}

constexpr float kLog2e    = 1.4426950408889634f;
constexpr float kPreScale = 2.0f * kLog2e;   // tanh(x) = 1 - 2/(1 + exp2(kPreScale*x))

// ---------------------------------------------------------------------------
// K0: transpose W_q, W_k into f4-major float4 tiles:
//   wt[mat][f4][h] = float4{ W[h][4*f4 .. 4*f4+3] }
// so proj's W loads (lane = h) are 1KB-coalesced instead of 4-8x line-inflated.
// ---------------------------------------------------------------------------
__global__ __launch_bounds__(256) void transw_kernel(
    const float* __restrict__ W_q, const float* __restrict__ W_k,
    float4* __restrict__ wt)
{
    const int bid = blockIdx.x;          // 16 = 2 mats * 8 f4-groups
    const int mat = bid & 1;
    const int f4b = (bid >> 1) * 8;
    const float4* W4 = (const float4*)(mat ? W_k : W_q);
    float4* o = wt + (size_t)mat * 64 * NH;

    const int t  = threadIdx.x;
    const int h  = t & 127;
    const int fo = t >> 7;
    #pragma unroll
    for (int it = 0; it < 4; ++it) {
        const int f4 = f4b + fo + 2 * it;
        o[f4 * NH + h] = W4[h * 64 + f4];    // scattered read (tiny), coalesced write
    }
}

// ---------------------------------------------------------------------------
// K1: projections + exponentials, register-blocked, no LDS in the hot loop.
//   eq [row][h]  = exp2(kPreScale * (Q·Wq^T))   row-major [2048][128]
//   ekt[b][h][j] = exp2(kPreScale * (K·Wk^T))   transposed [4][128][512]
// 4 waves: (h-half = wid&1) x (row-half = wid>>1). lane = h within half.
// In-row quads are wave-uniform (rbase via readfirstlane -> scalar loads);
// Wt loads are 1KB coalesced; 8 row-accumulators live in registers so each
// W quad is reused 8x with ZERO LDS reads (R3's proj was LDS-pipe-bound).
// ek output goes through a small padded LDS tile for the transposed write.
// ---------------------------------------------------------------------------
__global__ __launch_bounds__(256) void proj_kernel(
    const float* __restrict__ queries, const float* __restrict__ keys,
    const float4* __restrict__ wt,
    float* __restrict__ eq, float* __restrict__ ekt)
{
    const int bid   = blockIdx.x;        // 256 = 2 mats * 128 row-tiles(16)
    const int which = bid & 1;
    const int rt    = bid >> 1;
    const int row0  = rt * 16;
    const float4* In4 = (const float4*)(which ? keys : queries);
    const float4* w4  = wt + (size_t)which * 64 * NH;

    __shared__ float et[16][NH + 1];     // +1 pad: transposed read is 2-way (free)

    const int t    = threadIdx.x;
    const int lane = t & 63;
    const int wid  = t >> 6;
    const int h    = (wid & 1) * 64 + lane;
    const int rb   = __builtin_amdgcn_readfirstlane((wid >> 1) * 8);

    float acc[8] = {0.f, 0.f, 0.f, 0.f, 0.f, 0.f, 0.f, 0.f};
    const float4* Inb = In4 + (size_t)(row0 + rb) * 64;
    #pragma unroll 4
    for (int f4 = 0; f4 < 64; ++f4) {
        const float4 w = w4[f4 * NH + h];            // coalesced 1KB
        #pragma unroll
        for (int k = 0; k < 8; ++k) {
            const float4 x = Inb[(size_t)k * 64 + f4];   // wave-uniform (s_load)
            acc[k] += w.x * x.x + w.y * x.y + w.z * x.z + w.w * x.w;
        }
    }

    if (which == 0) {
        #pragma unroll
        for (int k = 0; k < 8; ++k)
            eq[(size_t)(row0 + rb + k) * NH + h] = fexp2(kPreScale * acc[k]);
    } else {
        #pragma unroll
        for (int k = 0; k < 8; ++k)
            et[rb + k][h] = fexp2(kPreScale * acc[k]);
        __syncthreads();
        const int rl = t & 15;
        const int h0 = t >> 4;           // 16 h-slots per pass
        const int b  = row0 >> 9;        // 16-row tile never crosses a batch
        const int j0 = row0 & 511;
        #pragma unroll
        for (int pass = 0; pass < 8; ++pass) {
            const int hh = h0 + 16 * pass;
            ekt[((size_t)b * NH + hh) * LK + j0 + rl] = et[rl][hh];
        }
    }
}

// ---------------------------------------------------------------------------
// K2: scores -> UNNORMALIZED softmax numerators p = exp(s - M).
// M = sum_h |W_v[h]| >= max possible score (|tanh|<1), so p <= 1 and the
// row-max reduction is unnecessary (identical after normalization; smallest
// p ~ e^-18, comfortably fp32-normal).  Block = (b, 8-query tile, 64-key
// chunk); wave owns 2 queries sharing every Ek column load; inactive chunks
// exit immediately.  p written into the attn region of d_out.
// ---------------------------------------------------------------------------
__global__ __launch_bounds__(256, 8) void score_kernel(
    const float* __restrict__ eq, const float* __restrict__ ekt,
    const int* __restrict__ valid_lens, const float* __restrict__ W_v,
    float* __restrict__ pout)
{
    const int id  = blockIdx.x;          // 2048 = 64 it * (4 b * 8 jc)
    const int it  = id & 63;
    const int bjc = id >> 6;
    const int b   = bjc >> 3;
    const int jc  = bjc & 7;
    const int vl  = valid_lens[b];
    if (jc * 64 >= vl) return;           // uniform early exit

    __shared__ float q_lds[8][NH];
    __shared__ float wv[NH];

    const int t  = threadIdx.x;
    const int i0 = it * 8;
    #pragma unroll
    for (int r = 0; r < 4; ++r)
        ((float*)q_lds)[t + 256 * r] = eq[(size_t)(b * LQ + i0) * NH + t + 256 * r];
    if (t < NH) wv[t] = W_v[t];
    __syncthreads();

    const int wid  = t >> 6;
    const int lane = t & 63;
    const float4* qa4 = (const float4*)q_lds[2 * wid];
    const float4* qb4 = (const float4*)q_lds[2 * wid + 1];
    const float4* wv4 = (const float4*)wv;

    float sumW = 0.f, sumA = 0.f;
    #pragma unroll 8
    for (int h4 = 0; h4 < NH / 4; ++h4) {
        const float4 w = wv4[h4];
        sumW += (w.x + w.y) + (w.z + w.w);
        sumA += (fabsf(w.x) + fabsf(w.y)) + (fabsf(w.z) + fabsf(w.w));
    }

    const float* pk = ekt + (size_t)b * NH * LK + jc * 64 + lane;
    float aA0 = 0.f, aA1 = 0.f, aA2 = 0.f, aA3 = 0.f;
    float aB0 = 0.f, aB1 = 0.f, aB2 = 0.f, aB3 = 0.f;
    #pragma unroll 4
    for (int h4 = 0; h4 < NH / 4; ++h4) {
        const float e0 = pk[(size_t)(4 * h4 + 0) * LK];   // coalesced 256B
        const float e1 = pk[(size_t)(4 * h4 + 1) * LK];
        const float e2 = pk[(size_t)(4 * h4 + 2) * LK];
        const float e3 = pk[(size_t)(4 * h4 + 3) * LK];
        const float4 w  = wv4[h4];
        const float4 qa = qa4[h4];
        const float4 qb = qb4[h4];
        aA0 = __builtin_fmaf(w.x, frcp(__builtin_fmaf(qa.x, e0, 1.f)), aA0);
        aA1 = __builtin_fmaf(w.y, frcp(__builtin_fmaf(qa.y, e1, 1.f)), aA1);
        aA2 = __builtin_fmaf(w.z, frcp(__builtin_fmaf(qa.z, e2, 1.f)), aA2);
        aA3 = __builtin_fmaf(w.w, frcp(__builtin_fmaf(qa.w, e3, 1.f)), aA3);
        aB0 = __builtin_fmaf(w.x, frcp(__builtin_fmaf(qb.x, e0, 1.f)), aB0);
        aB1 = __builtin_fmaf(w.y, frcp(__builtin_fmaf(qb.y, e1, 1.f)), aB1);
        aB2 = __builtin_fmaf(w.z, frcp(__builtin_fmaf(qb.z, e2, 1.f)), aB2);
        aB3 = __builtin_fmaf(w.w, frcp(__builtin_fmaf(qb.w, e3, 1.f)), aB3);
    }
    const float sA = __builtin_fmaf(-2.f, (aA0 + aA1) + (aA2 + aA3), sumW);
    const float sB = __builtin_fmaf(-2.f, (aB0 + aB1) + (aB2 + aB3), sumW);
    const float pA = fexp2((sA - sumA) * kLog2e);
    const float pB = fexp2((sB - sumA) * kLog2e);

    const int ra = i0 + 2 * wid;
    pout[((size_t)b * LQ + ra)     * LK + jc * 64 + lane] = pA;
    pout[((size_t)b * LQ + ra + 1) * LK + jc * 64 + lane] = pB;
}

// ---------------------------------------------------------------------------
// K3: normalize (sum only, no max/exp needed) + attn write + PV.
// Block = (b, 8 queries), 1024 threads = 16 waves.
// Phase A: wave (qi = w&7, half g = w>>3) loads p for slices {g, g+2, g+4,
//   g+6}, masks j>=vl to 0, shfl+LDS sum, writes attn to global AND to
//   attn_t[j][qi] (q-vectorized for PV).
// Phase B: wave w owns j-strip [32w, 32w+32); lane owns a float4 of columns;
//   per j: 2 uniform b128 reads give attn for ALL 8 queries, 1 coalesced 1KB
//   values load, 32 fma. Partials reduced via two-round pacc in LDS.
// ---------------------------------------------------------------------------
__global__ __launch_bounds__(1024) void normpv_kernel(
    const float* __restrict__ values, const int* __restrict__ valid_lens,
    float* __restrict__ out, float* __restrict__ attn_out /* = p in */)
{
    const int blk = blockIdx.x;          // 256 = NB * 64
    const int b   = blk >> 6;
    const int i0  = (blk & 63) * 8;

    __shared__ float  attn_t[LK][12];    // stride 48B: 16B-aligned float4 rows
    __shared__ float4 pacc[8][8][VD / 4];
    __shared__ float  reds[16];

    const int t    = threadIdx.x;
    const int wid  = t >> 6;
    const int lane = t & 63;
    const int vl   = valid_lens[b];

    // ---- Phase A: sum + normalize + attn writes ----
    const int qi = wid & 7;
    const int g  = wid >> 3;
    float* arow = attn_out + (size_t)(b * LQ + i0 + qi) * LK;

    float p[4];
    float sum = 0.f;
    #pragma unroll
    for (int u = 0; u < 4; ++u) {
        const int jj = g + 2 * u;
        const int j  = jj * 64 + lane;
        float e = 0.f;
        if (jj * 64 < vl) {              // wave-uniform
            e = arow[j];
            if (j >= vl) e = 0.f;        // mask tail lanes of boundary chunk
        }
        p[u] = e;
        sum += e;
    }
    #pragma unroll
    for (int off = 1; off < 64; off <<= 1)
        sum += __shfl_xor(sum, off, 64);
    if (lane == 0) reds[wid] = sum;
    __syncthreads();
    const float rs = frcp(reds[qi] + reds[qi + 8]);

    #pragma unroll
    for (int u = 0; u < 4; ++u) {
        const int j = (g + 2 * u) * 64 + lane;
        const float a = p[u] * rs;
        arow[j]       = a;               // coalesced; zeros beyond vl
        attn_t[j][qi] = a;
    }
    __syncthreads();

    // ---- Phase B: PV ----
    const int j0 = wid * 32;
    const int j1 = min(j0 + 32, vl);     // attn_t is exactly 0 in [vl, LK)
    float4 acc4[8];
    #pragma unroll
    for (int q = 0; q < 8; ++q) acc4[q] = float4{0.f, 0.f, 0.f, 0.f};

    const float4* v4 = (const float4*)(values + (size_t)b * LK * VD);
    for (int j = j0; j < j1; ++j) {
        const float4 a0 = *(const float4*)&attn_t[j][0];   // q0..3 (uniform)
        const float4 a1 = *(const float4*)&attn_t[j][4];   // q4..7 (uniform)
        const float4 vv = v4[(size_t)j * 64 + lane];       // coalesced 1KB
        fma4(acc4[0], a0.x, vv); fma4(acc4[1], a0.y, vv);
        fma4(acc4[2], a0.z, vv); fma4(acc4[3], a0.w, vv);
        fma4(acc4[4], a1.x, vv); fma4(acc4[5], a1.y, vv);
        fma4(acc4[6], a1.z, vv); fma4(acc4[7], a1.w, vv);
    }

    if (wid < 8) {
        #pragma unroll
        for (int q = 0; q < 8; ++q) pacc[wid][q][lane] = acc4[q];
    }
    __syncthreads();
    if (wid >= 8) {
        #pragma unroll
        for (int q = 0; q < 8; ++q) {
            const float4 pv = pacc[wid - 8][q][lane];
            pacc[wid - 8][q][lane] =
                float4{pv.x + acc4[q].x, pv.y + acc4[q].y,
                       pv.z + acc4[q].z, pv.w + acc4[q].w};
        }
    }
    __syncthreads();

    {   // final reduce: thread -> (q, cols c and c+128)
        const int q = t >> 7;            // 0..7
        const int c = t & 127;
        float s0 = 0.f, s1 = 0.f;
        #pragma unroll
        for (int k = 0; k < 8; ++k) {
            const float* pf = (const float*)&pacc[k][q][0];
            s0 += pf[c];
            s1 += pf[c + 128];
        }
        float* orow = out + (size_t)(b * LQ + i0 + q) * VD;
        orow[c]       = s0;
        orow[c + 128] = s1;
    }
}

// ---------------------------------------------------------------------------
extern "C" void kernel_launch(void* const* d_in, const int* in_sizes, int n_in,
                              void* d_out, int out_size, void* d_ws, size_t ws_size,
                              hipStream_t stream)
{
    const float* queries    = (const float*)d_in[0];
    const float* keys       = (const float*)d_in[1];
    const float* values     = (const float*)d_in[2];
    const int*   valid_lens = (const int*)  d_in[3];
    const float* W_q        = (const float*)d_in[4];
    const float* W_k        = (const float*)d_in[5];
    const float* W_v        = (const float*)d_in[6];

    float* out      = (float*)d_out;                       // [NB, LQ, VD]
    float* attn_out = out + (size_t)NB * LQ * VD;          // [NB, LQ, LK]

    float*  eq  = (float*)d_ws;                            // [2048][128]  1MB
    float*  ekt = eq + (size_t)NB * LQ * NH;               // [4][128][512] 1MB
    float4* wt  = (float4*)(ekt + (size_t)NB * NH * LK);   // [2][64][128] 256KB

    transw_kernel<<<16,   256, 0, stream>>>(W_q, W_k, wt);
    proj_kernel  <<<256,  256, 0, stream>>>(queries, keys, wt, eq, ekt);
    score_kernel <<<2048, 256, 0, stream>>>(eq, ekt, valid_lens, W_v, attn_out);
    normpv_kernel<<<256, 1024, 0, stream>>>(values, valid_lens, out, attn_out);
}